// Round 3
// baseline (162.400 us; speedup 1.0000x reference)
//
#include <hip/hip_runtime.h>

// B=32, M=32, C=1024, R=28.
// Single fused kernel: block = (batch b, c-tile of 128 channels).
//   Phase A: col[m,r]  = sum_i Masks[b,m,i,r]   (redundant per c-tile, 100 KB, L3-served)
//   Phase B: row[c,k]  = sum_j F[b,c,k,j]       (401 KB per block, strided float4,
//                                                98 independent loads/thread in flight)
//   Phase C: S[b,m,c]  = (1/784) sum_k col[m,k] * row[c,k]  -> d_out directly.
// No workspace, no second launch, one __syncthreads.
#define Rr 28
#define Bb 32
#define Mm 32
#define Cc 1024
#define CT 128            // channels per block

__global__ __launch_bounds__(256) void fused_pool(
    const float* __restrict__ F, const float* __restrict__ Mk,
    float* __restrict__ S) {
    __shared__ float col_s[Mm * 29];   // 3712 B  (stride 29: conflict-free reads)
    __shared__ float row_s[CT * 29];   // 14848 B
    const int b  = blockIdx.x >> 3;
    const int c0 = (blockIdx.x & 7) * CT;
    const int t  = threadIdx.x;

    // Phase A: Masks column sums for this batch.
    // idx lane-consecutive -> r consecutive (28-float runs), decent coalescing.
    const float* Mb = Mk + (size_t)b * (Mm * Rr * Rr);
    for (int idx = t; idx < Mm * Rr; idx += 256) {
        int m = idx / Rr, r = idx - m * Rr;
        const float* p = Mb + m * (Rr * Rr) + r;
        float s = 0.f;
#pragma unroll
        for (int i = 0; i < Rr; ++i) s += p[i * Rr];
        col_s[m * 29 + r] = s;
    }

    // Phase B: F row sums for this c-tile. 128*28 = 3584 rows, 14 per thread.
    // Each row = 7 float4 (112 B, always 16B-aligned). All 98 loads/thread are
    // independent and unrolled -> deep MLP, no sync inside the loop.
    const float* Fb = F + ((size_t)b * Cc + c0) * (Rr * Rr);
#pragma unroll
    for (int i = 0; i < 14; ++i) {
        int rid = t + 256 * i;                      // 0..3583
        const float4* p = (const float4*)(Fb + (size_t)rid * Rr);
        float s = 0.f;
#pragma unroll
        for (int q = 0; q < 7; ++q) {
            float4 v = p[q];
            s += (v.x + v.y) + (v.z + v.w);
        }
        int c = rid / Rr, k = rid - c * Rr;
        row_s[c * 29 + k] = s;
    }
    __syncthreads();

    // Phase C: 16 m per thread; row_s read at lane-stride 29 (odd -> 2-way, free);
    // col_s read wave-uniform broadcast; stores are 128-consecutive-float spans.
    const int c  = t & (CT - 1);
    const int mh = t >> 7;                          // wave-uniform (waves 64-aligned)
    float rreg[Rr];
#pragma unroll
    for (int k = 0; k < Rr; ++k) rreg[k] = row_s[c * 29 + k];
    const float inv = 1.0f / (Rr * Rr);
    for (int m = mh; m < Mm; m += 2) {
        float acc = 0.f;
#pragma unroll
        for (int k = 0; k < Rr; ++k) acc += col_s[m * 29 + k] * rreg[k];
        S[((size_t)b * Mm + m) * Cc + c0 + c] = acc * inv;
    }
}

extern "C" void kernel_launch(void* const* d_in, const int* in_sizes, int n_in,
                              void* d_out, int out_size, void* d_ws, size_t ws_size,
                              hipStream_t stream) {
    const float* F  = (const float*)d_in[0];   // (B, C, R, R) fp32
    const float* Mk = (const float*)d_in[1];   // (B, M, R, R) fp32
    float* S = (float*)d_out;                  // (B, M, C) fp32
    fused_pool<<<Bb * (Cc / CT), 256, 0, stream>>>(F, Mk, S);
}